// Round 1
// baseline (3769.097 us; speedup 1.0000x reference)
//
#include <hip/hip_runtime.h>
#include <hip/hip_bf16.h>

#define NN 50000
#define NE 800000

typedef unsigned short u16;

__device__ __forceinline__ float bf2f(u16 v) {
    union { unsigned int u; float f; } c; c.u = ((unsigned int)v) << 16; return c.f;
}
__device__ __forceinline__ u16 f2bf(float f) {
    union { float f; unsigned int u; } c; c.f = f;
    unsigned int r = c.u + 0x7FFFu + ((c.u >> 16) & 1u);
    return (u16)(r >> 16);
}

// ---------------------------------------------------------------------------
// Edge MLP: in = [edge_attr(16) | x[src](16) | x[dst](16) | u(16)] = 64
// 64 -> 128 -> 128 -> 128 -> 128, ReLU between, final linear.
// Writes e_out, atomically scatters into agg[dst], accumulates e_sum.
// Block = 64 edges, 256 threads. Thread tile: 4 edges x 8 outputs.
// ---------------------------------------------------------------------------
__global__ __launch_bounds__(256, 2) void edge_mlp(
    const float* __restrict__ x, const float* __restrict__ ea,
    const float* __restrict__ u, const int* __restrict__ ei,
    const float* __restrict__ w1, const float* __restrict__ b1,
    const float* __restrict__ w2, const float* __restrict__ b2,
    const float* __restrict__ w3, const float* __restrict__ b3,
    const float* __restrict__ w4, const float* __restrict__ b4,
    float* __restrict__ e_out, float* __restrict__ agg, float* __restrict__ e_sum)
{
    __shared__ u16 act[2][128][68];   // [buf][k][m], padded stride 68 (136B, 8B-aligned rows)
    __shared__ u16 wl[128][128];      // [k][o] bf16 weights for current layer chunk
    __shared__ float bl[128];
    __shared__ float psum[128];

    const int tid = threadIdx.x;
    const int eb = blockIdx.x * 64;
    if (tid < 128) psum[tid] = 0.0f;

    // ---- stage input tile: thread -> edge m = tid&63, 16-k segment seg = tid>>6
    {
        const int m = tid & 63, seg = tid >> 6;
        const int e = eb + m;
        const float* sp;
        if (seg == 0)      sp = ea + (size_t)e * 16;
        else if (seg == 1) sp = x + (size_t)ei[e] * 16;        // src
        else if (seg == 2) sp = x + (size_t)ei[NE + e] * 16;   // dst
        else               sp = u;
        const float4* sp4 = (const float4*)sp;
        const int kb = seg * 16;
        #pragma unroll
        for (int q = 0; q < 4; ++q) {
            float4 v = sp4[q];
            act[0][kb + q * 4 + 0][m] = f2bf(v.x);
            act[0][kb + q * 4 + 1][m] = f2bf(v.y);
            act[0][kb + q * 4 + 2][m] = f2bf(v.z);
            act[0][kb + q * 4 + 3][m] = f2bf(v.w);
        }
    }

    const int og = tid & 15, mg = tid >> 4;
    const int o0 = og * 8, m0 = mg * 4;
    const float* Ws[4] = { w1, w2, w3, w4 };
    const float* Bs[4] = { b1, b2, b3, b4 };
    const int    Ks[4] = { 64, 128, 128, 128 };

    int cur = 0;
    float val[4][8];
    for (int L = 0; L < 4; ++L) {
        const int K = Ks[L];
        float acc[4][8];
        #pragma unroll
        for (int i = 0; i < 4; ++i)
            #pragma unroll
            for (int j = 0; j < 8; ++j) acc[i][j] = 0.0f;

        // single chunk (K <= 128) weight staging + compute
        {
            const float4* wp = (const float4*)Ws[L];
            u16* wflat = &wl[0][0];
            const int n4 = (K * 128) / 4;
            for (int idx = tid; idx < n4; idx += 256) {
                float4 v = wp[idx];
                u16* d = wflat + idx * 4;
                d[0] = f2bf(v.x); d[1] = f2bf(v.y); d[2] = f2bf(v.z); d[3] = f2bf(v.w);
            }
            if (tid < 128) bl[tid] = Bs[L][tid];
            __syncthreads();   // weights + act[cur] ready

            #pragma unroll 4
            for (int k = 0; k < K; ++k) {
                ushort4 a4 = *(const ushort4*)&act[cur][k][m0];
                ushort4 wa = *(const ushort4*)&wl[k][o0];
                ushort4 wb = *(const ushort4*)&wl[k][o0 + 4];
                float av[4] = { bf2f(a4.x), bf2f(a4.y), bf2f(a4.z), bf2f(a4.w) };
                float wv[8] = { bf2f(wa.x), bf2f(wa.y), bf2f(wa.z), bf2f(wa.w),
                                bf2f(wb.x), bf2f(wb.y), bf2f(wb.z), bf2f(wb.w) };
                #pragma unroll
                for (int i = 0; i < 4; ++i)
                    #pragma unroll
                    for (int j = 0; j < 8; ++j)
                        acc[i][j] += av[i] * wv[j];
            }
            __syncthreads();   // all reads of wl/act done before anyone overwrites
        }

        if (L < 3) {
            #pragma unroll
            for (int j = 0; j < 8; ++j) {
                const int o = o0 + j;
                const float b = bl[o];
                u16* d = &act[cur ^ 1][o][m0];
                d[0] = f2bf(fmaxf(acc[0][j] + b, 0.0f));
                d[1] = f2bf(fmaxf(acc[1][j] + b, 0.0f));
                d[2] = f2bf(fmaxf(acc[2][j] + b, 0.0f));
                d[3] = f2bf(fmaxf(acc[3][j] + b, 0.0f));
            }
            cur ^= 1;
            // no barrier needed here: next layer's staging barrier orders act writes
        } else {
            #pragma unroll
            for (int i = 0; i < 4; ++i)
                #pragma unroll
                for (int j = 0; j < 8; ++j)
                    val[i][j] = acc[i][j] + bl[o0 + j];
        }
    }

    // ---- store e_out, scatter agg, column partial sums
    #pragma unroll
    for (int i = 0; i < 4; ++i) {
        const int e = eb + m0 + i;
        float4 r0 = make_float4(val[i][0], val[i][1], val[i][2], val[i][3]);
        float4 r1 = make_float4(val[i][4], val[i][5], val[i][6], val[i][7]);
        float4* op = (float4*)&e_out[(size_t)e * 128 + o0];
        op[0] = r0; op[1] = r1;
        const int d = ei[NE + e];
        float* ap = &agg[(size_t)d * 128 + o0];
        #pragma unroll
        for (int j = 0; j < 8; ++j) atomicAdd(ap + j, val[i][j]);
    }
    #pragma unroll
    for (int j = 0; j < 8; ++j)
        atomicAdd(&psum[o0 + j], val[0][j] + val[1][j] + val[2][j] + val[3][j]);
    __syncthreads();
    if (tid < 128) atomicAdd(&e_sum[tid], psum[tid]);
}

// ---------------------------------------------------------------------------
// Node MLP: in = [x(16) | agg(128) | u(16)] = 160 -> 128^4
// ---------------------------------------------------------------------------
__global__ __launch_bounds__(256, 2) void node_mlp(
    const float* __restrict__ x, const float* __restrict__ u,
    const float* __restrict__ agg,
    const float* __restrict__ w1, const float* __restrict__ b1,
    const float* __restrict__ w2, const float* __restrict__ b2,
    const float* __restrict__ w3, const float* __restrict__ b3,
    const float* __restrict__ w4, const float* __restrict__ b4,
    float* __restrict__ n_out, float* __restrict__ n_sum)
{
    __shared__ u16 act[2][160][68];
    __shared__ u16 wl[128][128];
    __shared__ float bl[128];
    __shared__ float psum[128];

    const int tid = threadIdx.x;
    const int nb = blockIdx.x * 64;
    if (tid < 128) psum[tid] = 0.0f;

    {
        const int m = tid & 63, seg = tid >> 6;
        const int node = nb + m;
        const bool valid = (node < NN);
        for (int kk = seg * 16; kk < 160; kk += 64) {
            float4 v0, v1, v2, v3;
            if (!valid) {
                v0 = v1 = v2 = v3 = make_float4(0.f, 0.f, 0.f, 0.f);
            } else if (kk == 0) {
                const float4* sp = (const float4*)(x + (size_t)node * 16);
                v0 = sp[0]; v1 = sp[1]; v2 = sp[2]; v3 = sp[3];
            } else if (kk < 144) {
                const float4* sp = (const float4*)(agg + (size_t)node * 128 + (kk - 16));
                v0 = sp[0]; v1 = sp[1]; v2 = sp[2]; v3 = sp[3];
            } else {
                const float4* sp = (const float4*)u;
                v0 = sp[0]; v1 = sp[1]; v2 = sp[2]; v3 = sp[3];
            }
            float4 vs[4] = { v0, v1, v2, v3 };
            #pragma unroll
            for (int q = 0; q < 4; ++q) {
                act[0][kk + q * 4 + 0][tid & 63] = f2bf(vs[q].x);
                act[0][kk + q * 4 + 1][tid & 63] = f2bf(vs[q].y);
                act[0][kk + q * 4 + 2][tid & 63] = f2bf(vs[q].z);
                act[0][kk + q * 4 + 3][tid & 63] = f2bf(vs[q].w);
            }
        }
    }

    const int og = tid & 15, mg = tid >> 4;
    const int o0 = og * 8, m0 = mg * 4;
    const float* Ws[4] = { w1, w2, w3, w4 };
    const float* Bs[4] = { b1, b2, b3, b4 };
    const int    Ks[4] = { 160, 128, 128, 128 };

    int cur = 0;
    float val[4][8];
    for (int L = 0; L < 4; ++L) {
        const int K = Ks[L];
        float acc[4][8];
        #pragma unroll
        for (int i = 0; i < 4; ++i)
            #pragma unroll
            for (int j = 0; j < 8; ++j) acc[i][j] = 0.0f;

        for (int k0 = 0; k0 < K; k0 += 128) {
            const int kc = (K - k0 < 128) ? (K - k0) : 128;
            const float4* wp = (const float4*)(Ws[L] + (size_t)k0 * 128);
            u16* wflat = &wl[0][0];
            const int n4 = (kc * 128) / 4;
            for (int idx = tid; idx < n4; idx += 256) {
                float4 v = wp[idx];
                u16* d = wflat + idx * 4;
                d[0] = f2bf(v.x); d[1] = f2bf(v.y); d[2] = f2bf(v.z); d[3] = f2bf(v.w);
            }
            if (k0 == 0 && tid < 128) bl[tid] = Bs[L][tid];
            __syncthreads();

            #pragma unroll 4
            for (int k = 0; k < kc; ++k) {
                ushort4 a4 = *(const ushort4*)&act[cur][k0 + k][m0];
                ushort4 wa = *(const ushort4*)&wl[k][o0];
                ushort4 wb = *(const ushort4*)&wl[k][o0 + 4];
                float av[4] = { bf2f(a4.x), bf2f(a4.y), bf2f(a4.z), bf2f(a4.w) };
                float wv[8] = { bf2f(wa.x), bf2f(wa.y), bf2f(wa.z), bf2f(wa.w),
                                bf2f(wb.x), bf2f(wb.y), bf2f(wb.z), bf2f(wb.w) };
                #pragma unroll
                for (int i = 0; i < 4; ++i)
                    #pragma unroll
                    for (int j = 0; j < 8; ++j)
                        acc[i][j] += av[i] * wv[j];
            }
            __syncthreads();
        }

        if (L < 3) {
            #pragma unroll
            for (int j = 0; j < 8; ++j) {
                const int o = o0 + j;
                const float b = bl[o];
                u16* d = &act[cur ^ 1][o][m0];
                d[0] = f2bf(fmaxf(acc[0][j] + b, 0.0f));
                d[1] = f2bf(fmaxf(acc[1][j] + b, 0.0f));
                d[2] = f2bf(fmaxf(acc[2][j] + b, 0.0f));
                d[3] = f2bf(fmaxf(acc[3][j] + b, 0.0f));
            }
            cur ^= 1;
        } else {
            #pragma unroll
            for (int i = 0; i < 4; ++i)
                #pragma unroll
                for (int j = 0; j < 8; ++j)
                    val[i][j] = acc[i][j] + bl[o0 + j];
        }
    }

    #pragma unroll
    for (int i = 0; i < 4; ++i) {
        const int node = nb + m0 + i;
        if (node < NN) {
            float4 r0 = make_float4(val[i][0], val[i][1], val[i][2], val[i][3]);
            float4 r1 = make_float4(val[i][4], val[i][5], val[i][6], val[i][7]);
            float4* op = (float4*)&n_out[(size_t)node * 128 + o0];
            op[0] = r0; op[1] = r1;
            #pragma unroll
            for (int j = 0; j < 8; ++j)
                atomicAdd(&psum[o0 + j], val[i][j]);
        }
    }
    __syncthreads();
    if (tid < 128) atomicAdd(&n_sum[tid], psum[tid]);
}

// ---------------------------------------------------------------------------
// Global MLP: in = [u(16) | n_sum(128) | e_sum(128)] = 272 -> 128^4 (fp32)
// ---------------------------------------------------------------------------
__global__ void global_mlp(
    const float* __restrict__ u,
    const float* __restrict__ w1, const float* __restrict__ b1,
    const float* __restrict__ w2, const float* __restrict__ b2,
    const float* __restrict__ w3, const float* __restrict__ b3,
    const float* __restrict__ w4, const float* __restrict__ b4,
    const float* __restrict__ nsum, const float* __restrict__ esum,
    float* __restrict__ g_out)
{
    __shared__ float in_s[272];
    __shared__ float h[2][128];
    const int t = threadIdx.x;   // 128 threads
    if (t < 16) in_s[t] = u[t];
    in_s[16 + t] = nsum[t];
    in_s[144 + t] = esum[t];
    __syncthreads();

    float a = b1[t];
    for (int k = 0; k < 272; ++k) a += in_s[k] * w1[(size_t)k * 128 + t];
    h[0][t] = fmaxf(a, 0.0f);
    __syncthreads();

    a = b2[t];
    for (int k = 0; k < 128; ++k) a += h[0][k] * w2[k * 128 + t];
    h[1][t] = fmaxf(a, 0.0f);
    __syncthreads();

    a = b3[t];
    for (int k = 0; k < 128; ++k) a += h[1][k] * w3[k * 128 + t];
    h[0][t] = fmaxf(a, 0.0f);
    __syncthreads();

    a = b4[t];
    for (int k = 0; k < 128; ++k) a += h[0][k] * w4[k * 128 + t];
    g_out[t] = a;
}

extern "C" void kernel_launch(void* const* d_in, const int* in_sizes, int n_in,
                              void* d_out, int out_size, void* d_ws, size_t ws_size,
                              hipStream_t stream)
{
    const float* x  = (const float*)d_in[0];
    const float* ea = (const float*)d_in[1];
    const float* u  = (const float*)d_in[2];
    const int*   ei = (const int*)d_in[3];

    const float* ew1 = (const float*)d_in[4];
    const float* eb1 = (const float*)d_in[5];
    const float* ew2 = (const float*)d_in[6];
    const float* eb2 = (const float*)d_in[7];
    const float* ew3 = (const float*)d_in[8];
    const float* eb3 = (const float*)d_in[9];
    const float* ew4 = (const float*)d_in[10];
    const float* eb4 = (const float*)d_in[11];

    const float* nw1 = (const float*)d_in[12];
    const float* nb1 = (const float*)d_in[13];
    const float* nw2 = (const float*)d_in[14];
    const float* nb2 = (const float*)d_in[15];
    const float* nw3 = (const float*)d_in[16];
    const float* nb3 = (const float*)d_in[17];
    const float* nw4 = (const float*)d_in[18];
    const float* nb4 = (const float*)d_in[19];

    const float* gw1 = (const float*)d_in[20];
    const float* gb1 = (const float*)d_in[21];
    const float* gw2 = (const float*)d_in[22];
    const float* gb2 = (const float*)d_in[23];
    const float* gw3 = (const float*)d_in[24];
    const float* gb3 = (const float*)d_in[25];
    const float* gw4 = (const float*)d_in[26];
    const float* gb4 = (const float*)d_in[27];

    float* e_out = (float*)d_out;
    float* n_out = e_out + (size_t)NE * 128;
    float* g_out = n_out + (size_t)NN * 128;

    float* agg  = (float*)d_ws;                  // [NN][128] fp32
    float* esum = agg + (size_t)NN * 128;        // [128]
    float* nsum = esum + 128;                    // [128]

    hipMemsetAsync(d_ws, 0, ((size_t)NN * 128 + 256) * sizeof(float), stream);

    edge_mlp<<<NE / 64, 256, 0, stream>>>(x, ea, u, ei,
        ew1, eb1, ew2, eb2, ew3, eb3, ew4, eb4, e_out, agg, esum);

    node_mlp<<<(NN + 63) / 64, 256, 0, stream>>>(x, u, agg,
        nw1, nb1, nw2, nb2, nw3, nb3, nw4, nb4, n_out, nsum);

    global_mlp<<<1, 128, 0, stream>>>(u,
        gw1, gb1, gw2, gb2, gw3, gb3, gw4, gb4, nsum, esum, g_out);
}

// Round 2
// 1002.945 us; speedup vs baseline: 3.7580x; 3.7580x over previous
//
#include <hip/hip_runtime.h>

#define NN 50000
#define NE 800000

typedef unsigned short u16;
typedef __attribute__((ext_vector_type(8))) short bf8;     // 8 x bf16 (4 VGPR)
typedef __attribute__((ext_vector_type(4))) float f32x4;

__device__ __forceinline__ u16 f2bf(float f) {
    union { float f; unsigned int u; } c; c.f = f;
    unsigned int r = c.u + 0x7FFFu + ((c.u >> 16) & 1u);
    return (u16)(r >> 16);
}

// ---------------------------------------------------------------------------
// Weight convert: w[K][128] fp32 -> wT[128][K] bf16 (transposed, for B-frags)
// ---------------------------------------------------------------------------
__global__ void conv_w(const float* __restrict__ w, u16* __restrict__ wT, int K) {
    int idx = blockIdx.x * 256 + threadIdx.x;
    if (idx < K * 128) {
        int k = idx >> 7, o = idx & 127;
        wT[(size_t)o * K + k] = f2bf(w[idx]);
    }
}

// ---------------------------------------------------------------------------
// CSR build: count -> scan (2-level) -> fill
// ---------------------------------------------------------------------------
__global__ void count_k(const int* __restrict__ ei, int* __restrict__ counts) {
    int e = blockIdx.x * 256 + threadIdx.x;
    if (e < NE) atomicAdd(&counts[ei[NE + e]], 1);
}

__global__ void scan_a(const int* __restrict__ counts, int* __restrict__ scanned,
                       int* __restrict__ bsum) {
    __shared__ int s[256];
    int t = threadIdx.x, i = blockIdx.x * 256 + t;
    int v = (i < NN) ? counts[i] : 0;
    s[t] = v;
    __syncthreads();
    for (int off = 1; off < 256; off <<= 1) {
        int add = (t >= off) ? s[t - off] : 0;
        __syncthreads();
        s[t] += add;
        __syncthreads();
    }
    if (i < NN) scanned[i] = s[t] - v;   // exclusive within block
    if (t == 255) bsum[blockIdx.x] = s[255];
}

__global__ void scan_b(const int* __restrict__ bsum, int* __restrict__ boff, int nb) {
    __shared__ int s[256];
    int t = threadIdx.x;
    int v = (t < nb) ? bsum[t] : 0;
    s[t] = v;
    __syncthreads();
    for (int off = 1; off < 256; off <<= 1) {
        int add = (t >= off) ? s[t - off] : 0;
        __syncthreads();
        s[t] += add;
        __syncthreads();
    }
    if (t < nb) boff[t] = s[t] - v;      // exclusive block offsets
}

__global__ void scan_c(const int* __restrict__ scanned, const int* __restrict__ boff,
                       int* __restrict__ starts, int* __restrict__ cursor) {
    int i = blockIdx.x * 256 + threadIdx.x;
    if (i < NN) {
        int v = scanned[i] + boff[blockIdx.x];
        starts[i] = v;
        cursor[i] = v;
    }
    if (i == 0) starts[NN] = NE;
}

__global__ void fill_k(const int* __restrict__ ei, int* __restrict__ cursor,
                       int* __restrict__ elist) {
    int e = blockIdx.x * 256 + threadIdx.x;
    if (e < NE) {
        int d = ei[NE + e];
        int pos = atomicAdd(&cursor[d], 1);
        elist[pos] = e;
    }
}

// ---------------------------------------------------------------------------
// Gather: agg[n][:] = sum over incident edges of e_out[e][:]
// ---------------------------------------------------------------------------
__global__ __launch_bounds__(128) void gather_agg(const float* __restrict__ e_out,
        const int* __restrict__ starts, const int* __restrict__ elist,
        float* __restrict__ agg) {
    int n = blockIdx.x, t = threadIdx.x;
    int s = starts[n], en = starts[n + 1];
    float a = 0.f;
    for (int j = s; j < en; ++j)
        a += e_out[(size_t)elist[j] * 128 + t];
    agg[(size_t)n * 128 + t] = a;
}

// ---------------------------------------------------------------------------
// Edge MLP (MFMA): tile M=128 edges x N=128, 4 waves 2x2, wave tile 64x64.
// act: LDS [128][136] bf16 (single buffer; acc in regs across layer rewrite).
// weights: bf16 [O][K] in global ws, staged per 64-k chunk to wl[128][72].
// ---------------------------------------------------------------------------
__global__ __launch_bounds__(256, 2) void edge_mlp(
    const float* __restrict__ x, const float* __restrict__ ea,
    const float* __restrict__ u, const int* __restrict__ ei,
    const u16* __restrict__ wT,
    const float* __restrict__ b1, const float* __restrict__ b2,
    const float* __restrict__ b3, const float* __restrict__ b4,
    float* __restrict__ e_out, float* __restrict__ e_sum)
{
    __shared__ u16 act[128][136];   // row stride 272B: 16B-aligned, bank-balanced
    __shared__ u16 wl[128][72];     // row stride 144B
    __shared__ float bl[4][128];
    __shared__ float psum[128];

    const int tid = threadIdx.x;
    const int eb = blockIdx.x * 128;

    if (tid < 128) {
        bl[0][tid] = b1[tid]; bl[1][tid] = b2[tid];
        bl[2][tid] = b3[tid]; bl[3][tid] = b4[tid];
        psum[tid] = 0.f;
    }

    // ---- stage layer-1 input (cols 0..63): m=tid&127, seg=tid>>7 -> 32 cols
    {
        const int m = tid & 127, seg = tid >> 7;
        const int e = eb + m;
        const float *p0, *p1;
        if (seg == 0) { p0 = ea + (size_t)e * 16; p1 = x + (size_t)ei[e] * 16; }
        else          { p0 = x + (size_t)ei[NE + e] * 16; p1 = u; }
        const int kb = seg * 32;
        const float4* q0 = (const float4*)p0;
        const float4* q1 = (const float4*)p1;
        #pragma unroll
        for (int q = 0; q < 4; ++q) {
            float4 v = q0[q];
            ushort4 h; h.x = f2bf(v.x); h.y = f2bf(v.y); h.z = f2bf(v.z); h.w = f2bf(v.w);
            *(ushort4*)&act[m][kb + q * 4] = h;
        }
        #pragma unroll
        for (int q = 0; q < 4; ++q) {
            float4 v = q1[q];
            ushort4 h; h.x = f2bf(v.x); h.y = f2bf(v.y); h.z = f2bf(v.z); h.w = f2bf(v.w);
            *(ushort4*)&act[m][kb + 16 + q * 4] = h;
        }
    }

    const int lane = tid & 63;
    const int wv = tid >> 6;
    const int wm = (wv >> 1) * 64, wn = (wv & 1) * 64;
    const int lr = lane & 15;            // A-row / B-col / D-col within 16-tile
    const int lk = (lane >> 4) * 8;      // k offset within 32-k step
    const int lh = (lane >> 4) * 4;      // D-row group

    const int Ks[4] = {64, 128, 128, 128};
    const u16* wg = wT;

    for (int L = 0; L < 4; ++L) {
        const int K = Ks[L];
        f32x4 acc[4][4];
        #pragma unroll
        for (int i = 0; i < 4; ++i)
            #pragma unroll
            for (int j = 0; j < 4; ++j)
                acc[i][j] = (f32x4){0.f, 0.f, 0.f, 0.f};

        for (int kc0 = 0; kc0 < K; kc0 += 64) {
            // stage weight chunk: wl[o][0..63] = wT[o][kc0..kc0+63]
            #pragma unroll
            for (int q = 0; q < 4; ++q) {
                int idx = tid + q * 256;     // 1024 x 8-elem segs
                int o = idx >> 3, s = idx & 7;
                *(bf8*)&wl[o][s * 8] = *(const bf8*)&wg[(size_t)o * K + kc0 + s * 8];
            }
            __syncthreads();
            #pragma unroll
            for (int ks = 0; ks < 2; ++ks) {
                const int kl = ks * 32 + lk;
                bf8 af[4], wf[4];
                #pragma unroll
                for (int mt = 0; mt < 4; ++mt)
                    af[mt] = *(const bf8*)&act[wm + mt * 16 + lr][kc0 + kl];
                #pragma unroll
                for (int ot = 0; ot < 4; ++ot)
                    wf[ot] = *(const bf8*)&wl[wn + ot * 16 + lr][kl];
                #pragma unroll
                for (int mt = 0; mt < 4; ++mt)
                    #pragma unroll
                    for (int ot = 0; ot < 4; ++ot)
                        acc[mt][ot] = __builtin_amdgcn_mfma_f32_16x16x32_bf16(
                            af[mt], wf[ot], acc[mt][ot], 0, 0, 0);
            }
            __syncthreads();
        }
        wg += (size_t)K * 128;

        if (L < 3) {
            // bias+ReLU -> act (all reads of act for this layer are done)
            #pragma unroll
            for (int ot = 0; ot < 4; ++ot) {
                const int o = wn + ot * 16 + lr;
                const float bi = bl[L][o];
                #pragma unroll
                for (int mt = 0; mt < 4; ++mt)
                    #pragma unroll
                    for (int r = 0; r < 4; ++r)
                        act[wm + mt * 16 + lh + r][o] =
                            f2bf(fmaxf(acc[mt][ot][r] + bi, 0.f));
            }
            // next chunk's staging __syncthreads orders these writes before reads
        } else {
            #pragma unroll
            for (int ot = 0; ot < 4; ++ot) {
                const int o = wn + ot * 16 + lr;
                const float bi = bl[3][o];
                float cs = 0.f;
                #pragma unroll
                for (int mt = 0; mt < 4; ++mt)
                    #pragma unroll
                    for (int r = 0; r < 4; ++r) {
                        float v = acc[mt][ot][r] + bi;
                        e_out[(size_t)(eb + wm + mt * 16 + lh + r) * 128 + o] = v;
                        cs += v;
                    }
                atomicAdd(&psum[o], cs);
            }
        }
    }
    __syncthreads();
    if (tid < 128) atomicAdd(&e_sum[tid], psum[tid]);
}

// ---------------------------------------------------------------------------
// Node MLP (MFMA): same structure, K1=160, M=128 nodes/block with tail guard.
// ---------------------------------------------------------------------------
__global__ __launch_bounds__(256, 2) void node_mlp(
    const float* __restrict__ x, const float* __restrict__ u,
    const float* __restrict__ agg, const u16* __restrict__ wT,
    const float* __restrict__ b1, const float* __restrict__ b2,
    const float* __restrict__ b3, const float* __restrict__ b4,
    float* __restrict__ n_out, float* __restrict__ n_sum)
{
    __shared__ u16 act[128][168];   // row stride 336B: 16B-aligned
    __shared__ u16 wl[128][72];
    __shared__ float bl[4][128];
    __shared__ float psum[128];

    const int tid = threadIdx.x;
    const int nb = blockIdx.x * 128;

    if (tid < 128) {
        bl[0][tid] = b1[tid]; bl[1][tid] = b2[tid];
        bl[2][tid] = b3[tid]; bl[3][tid] = b4[tid];
        psum[tid] = 0.f;
    }

    // ---- stage layer-1 input: [x(16)|agg(128)|u(16)] -> cols 0..159
    {
        const int m = tid & 127, seg = tid >> 7;
        const int node = nb + m;
        const bool ok = node < NN;
        const int c0 = seg * 80;
        #pragma unroll
        for (int q = 0; q < 20; ++q) {
            const int c = c0 + q * 4;
            float4 v;
            if (!ok)          v = make_float4(0.f, 0.f, 0.f, 0.f);
            else if (c < 16)  v = *(const float4*)&x[(size_t)node * 16 + c];
            else if (c < 144) v = *(const float4*)&agg[(size_t)node * 128 + (c - 16)];
            else              v = *(const float4*)&u[c - 144];
            ushort4 h; h.x = f2bf(v.x); h.y = f2bf(v.y); h.z = f2bf(v.z); h.w = f2bf(v.w);
            *(ushort4*)&act[m][c] = h;
        }
    }

    const int lane = tid & 63;
    const int wv = tid >> 6;
    const int wm = (wv >> 1) * 64, wn = (wv & 1) * 64;
    const int lr = lane & 15, lk = (lane >> 4) * 8, lh = (lane >> 4) * 4;

    const int Ks[4] = {160, 128, 128, 128};
    const u16* wg = wT;

    for (int L = 0; L < 4; ++L) {
        const int K = Ks[L];
        f32x4 acc[4][4];
        #pragma unroll
        for (int i = 0; i < 4; ++i)
            #pragma unroll
            for (int j = 0; j < 4; ++j)
                acc[i][j] = (f32x4){0.f, 0.f, 0.f, 0.f};

        for (int kc0 = 0; kc0 < K; kc0 += 64) {
            const int kc = (K - kc0 < 64) ? (K - kc0) : 64;   // 64 or 32
            const int sh = (kc == 64) ? 3 : 2;
            const int nsg = 1 << sh;   // kc/8
            for (int idx = tid; idx < (128 << sh); idx += 256) {
                int o = idx >> sh, s = idx & (nsg - 1);
                *(bf8*)&wl[o][s * 8] = *(const bf8*)&wg[(size_t)o * K + kc0 + s * 8];
            }
            __syncthreads();
            const int nks = kc >> 5;   // 2 or 1
            for (int ks = 0; ks < nks; ++ks) {
                const int kl = ks * 32 + lk;
                bf8 af[4], wf[4];
                #pragma unroll
                for (int mt = 0; mt < 4; ++mt)
                    af[mt] = *(const bf8*)&act[wm + mt * 16 + lr][kc0 + kl];
                #pragma unroll
                for (int ot = 0; ot < 4; ++ot)
                    wf[ot] = *(const bf8*)&wl[wn + ot * 16 + lr][kl];
                #pragma unroll
                for (int mt = 0; mt < 4; ++mt)
                    #pragma unroll
                    for (int ot = 0; ot < 4; ++ot)
                        acc[mt][ot] = __builtin_amdgcn_mfma_f32_16x16x32_bf16(
                            af[mt], wf[ot], acc[mt][ot], 0, 0, 0);
            }
            __syncthreads();
        }
        wg += (size_t)K * 128;

        if (L < 3) {
            #pragma unroll
            for (int ot = 0; ot < 4; ++ot) {
                const int o = wn + ot * 16 + lr;
                const float bi = bl[L][o];
                #pragma unroll
                for (int mt = 0; mt < 4; ++mt)
                    #pragma unroll
                    for (int r = 0; r < 4; ++r)
                        act[wm + mt * 16 + lh + r][o] =
                            f2bf(fmaxf(acc[mt][ot][r] + bi, 0.f));
            }
        } else {
            #pragma unroll
            for (int ot = 0; ot < 4; ++ot) {
                const int o = wn + ot * 16 + lr;
                const float bi = bl[3][o];
                float cs = 0.f;
                #pragma unroll
                for (int mt = 0; mt < 4; ++mt)
                    #pragma unroll
                    for (int r = 0; r < 4; ++r) {
                        const int node = nb + wm + mt * 16 + lh + r;
                        if (node < NN) {
                            float v = acc[mt][ot][r] + bi;
                            n_out[(size_t)node * 128 + o] = v;
                            cs += v;
                        }
                    }
                atomicAdd(&psum[o], cs);
            }
        }
    }
    __syncthreads();
    if (tid < 128) atomicAdd(&n_sum[tid], psum[tid]);
}

// ---------------------------------------------------------------------------
// Global MLP: in = [u(16) | n_sum(128) | e_sum(128)] = 272 -> 128^4 (fp32)
// ---------------------------------------------------------------------------
__global__ void global_mlp(
    const float* __restrict__ u,
    const float* __restrict__ w1, const float* __restrict__ b1,
    const float* __restrict__ w2, const float* __restrict__ b2,
    const float* __restrict__ w3, const float* __restrict__ b3,
    const float* __restrict__ w4, const float* __restrict__ b4,
    const float* __restrict__ nsum, const float* __restrict__ esum,
    float* __restrict__ g_out)
{
    __shared__ float in_s[272];
    __shared__ float h[2][128];
    const int t = threadIdx.x;   // 128 threads
    if (t < 16) in_s[t] = u[t];
    in_s[16 + t] = nsum[t];
    in_s[144 + t] = esum[t];
    __syncthreads();

    float a = b1[t];
    for (int k = 0; k < 272; ++k) a += in_s[k] * w1[(size_t)k * 128 + t];
    h[0][t] = fmaxf(a, 0.0f);
    __syncthreads();

    a = b2[t];
    for (int k = 0; k < 128; ++k) a += h[0][k] * w2[k * 128 + t];
    h[1][t] = fmaxf(a, 0.0f);
    __syncthreads();

    a = b3[t];
    for (int k = 0; k < 128; ++k) a += h[1][k] * w3[k * 128 + t];
    h[0][t] = fmaxf(a, 0.0f);
    __syncthreads();

    a = b4[t];
    for (int k = 0; k < 128; ++k) a += h[0][k] * w4[k * 128 + t];
    g_out[t] = a;
}

extern "C" void kernel_launch(void* const* d_in, const int* in_sizes, int n_in,
                              void* d_out, int out_size, void* d_ws, size_t ws_size,
                              hipStream_t stream)
{
    const float* x  = (const float*)d_in[0];
    const float* ea = (const float*)d_in[1];
    const float* u  = (const float*)d_in[2];
    const int*   ei = (const int*)d_in[3];

    const float* ew1 = (const float*)d_in[4];
    const float* eb1 = (const float*)d_in[5];
    const float* ew2 = (const float*)d_in[6];
    const float* eb2 = (const float*)d_in[7];
    const float* ew3 = (const float*)d_in[8];
    const float* eb3 = (const float*)d_in[9];
    const float* ew4 = (const float*)d_in[10];
    const float* eb4 = (const float*)d_in[11];

    const float* nw1 = (const float*)d_in[12];
    const float* nb1 = (const float*)d_in[13];
    const float* nw2 = (const float*)d_in[14];
    const float* nb2 = (const float*)d_in[15];
    const float* nw3 = (const float*)d_in[16];
    const float* nb3 = (const float*)d_in[17];
    const float* nw4 = (const float*)d_in[18];
    const float* nb4 = (const float*)d_in[19];

    const float* gw1 = (const float*)d_in[20];
    const float* gb1 = (const float*)d_in[21];
    const float* gw2 = (const float*)d_in[22];
    const float* gb2 = (const float*)d_in[23];
    const float* gw3 = (const float*)d_in[24];
    const float* gb3 = (const float*)d_in[25];
    const float* gw4 = (const float*)d_in[26];
    const float* gb4 = (const float*)d_in[27];

    float* e_out = (float*)d_out;
    float* n_out = e_out + (size_t)NE * 128;
    float* g_out = n_out + (size_t)NN * 128;

    // ---- workspace layout (bytes, all 16B-aligned)
    char* ws = (char*)d_ws;
    const size_t OFF_ESUM  = 25600000;            // after agg [NN][128] f32
    const size_t OFF_NSUM  = OFF_ESUM + 512;
    const size_t OFF_CNT   = OFF_NSUM + 512;
    const size_t OFF_SCN   = OFF_CNT + 200000;
    const size_t OFF_BSUM  = OFF_SCN + 200000;
    const size_t OFF_BOFF  = OFF_BSUM + 1024;
    const size_t OFF_START = OFF_BOFF + 1024;
    const size_t OFF_CUR   = OFF_START + 200064;
    const size_t OFF_ELIST = OFF_CUR + 200000;
    const size_t OFF_WTE   = OFF_ELIST + 3200000;
    const size_t OFF_WTN   = OFF_WTE + 114688;

    float* agg    = (float*)ws;
    float* esum   = (float*)(ws + OFF_ESUM);
    float* nsum   = (float*)(ws + OFF_NSUM);
    int*   counts = (int*)(ws + OFF_CNT);
    int*   scanned= (int*)(ws + OFF_SCN);
    int*   bsum   = (int*)(ws + OFF_BSUM);
    int*   boff   = (int*)(ws + OFF_BOFF);
    int*   starts = (int*)(ws + OFF_START);
    int*   cursor = (int*)(ws + OFF_CUR);
    int*   elist  = (int*)(ws + OFF_ELIST);
    u16*   wTe    = (u16*)(ws + OFF_WTE);
    u16*   wTn    = (u16*)(ws + OFF_WTN);

    // zero esum, nsum, counts in one shot (contiguous)
    hipMemsetAsync(ws + OFF_ESUM, 0, 512 + 512 + 200000, stream);

    // ---- weight conversion (bf16, transposed [O][K])
    conv_w<<<32, 256, 0, stream>>>(ew1, wTe, 64);
    conv_w<<<64, 256, 0, stream>>>(ew2, wTe + 64 * 128, 128);
    conv_w<<<64, 256, 0, stream>>>(ew3, wTe + 64 * 128 + 128 * 128, 128);
    conv_w<<<64, 256, 0, stream>>>(ew4, wTe + 64 * 128 + 2 * 128 * 128, 128);
    conv_w<<<80, 256, 0, stream>>>(nw1, wTn, 160);
    conv_w<<<64, 256, 0, stream>>>(nw2, wTn + 160 * 128, 128);
    conv_w<<<64, 256, 0, stream>>>(nw3, wTn + 160 * 128 + 128 * 128, 128);
    conv_w<<<64, 256, 0, stream>>>(nw4, wTn + 160 * 128 + 2 * 128 * 128, 128);

    // ---- CSR build
    count_k<<<3125, 256, 0, stream>>>(ei, counts);
    scan_a<<<196, 256, 0, stream>>>(counts, scanned, bsum);
    scan_b<<<1, 256, 0, stream>>>(bsum, boff, 196);
    scan_c<<<196, 256, 0, stream>>>(scanned, boff, starts, cursor);
    fill_k<<<3125, 256, 0, stream>>>(ei, cursor, elist);

    // ---- main pipeline
    edge_mlp<<<NE / 128, 256, 0, stream>>>(x, ea, u, ei, wTe,
        eb1, eb2, eb3, eb4, e_out, esum);
    gather_agg<<<NN, 128, 0, stream>>>(e_out, starts, elist, agg);
    node_mlp<<<(NN + 127) / 128, 256, 0, stream>>>(x, u, agg, wTn,
        nb1, nb2, nb3, nb4, n_out, nsum);
    global_mlp<<<1, 128, 0, stream>>>(u,
        gw1, gb1, gw2, gb2, gw3, gb3, gw4, gb4, nsum, esum, g_out);
}